// Round 12
// baseline (406.424 us; speedup 1.0000x reference)
//
#include <hip/hip_runtime.h>
#include <hip/hip_bf16.h>

#define NN_NODES 20000
#define NE_EDGES 500000
#define KTOT 48

typedef __bf16 bf16x8 __attribute__((ext_vector_type(8)));
typedef float f32x4 __attribute__((ext_vector_type(4)));

__device__ inline unsigned short bf16_rne(float x) {
    unsigned int u = __float_as_uint(x);
    u = (u + 0x7fffu + ((u >> 16) & 1u)) >> 16;
    return (unsigned short)u;
}

// ---------------------------------------------------------------------------
// Zero helper
// ---------------------------------------------------------------------------
__global__ void zero_kernel(int* __restrict__ p, int n) {
    int i = blockIdx.x * 256 + threadIdx.x;
    if (i < n) p[i] = 0;
}

// ---------------------------------------------------------------------------
// CSR build
// ---------------------------------------------------------------------------
__global__ void count_kernel(const int* __restrict__ ei, int* __restrict__ counts) {
    int e = blockIdx.x * 256 + threadIdx.x;
    if (e < NE_EDGES) atomicAdd(&counts[ei[NE_EDGES + e]], 1);
}

__global__ void scan_kernel(const int* __restrict__ counts, int* __restrict__ row_start) {
    __shared__ int part[256];
    const int CH = (NN_NODES + 255) / 256;
    int t = threadIdx.x;
    int begin = t * CH;
    int end = begin + CH;
    if (end > NN_NODES) end = NN_NODES;
    int sum = 0;
    for (int i = begin; i < end && i < NN_NODES; ++i) sum += counts[i];
    part[t] = sum;
    __syncthreads();
    for (int off = 1; off < 256; off <<= 1) {
        int v = (t >= off) ? part[t - off] : 0;
        __syncthreads();
        part[t] += v;
        __syncthreads();
    }
    int run = (t == 0) ? 0 : part[t - 1];
    for (int i = begin; i < end && i < NN_NODES; ++i) {
        row_start[i] = run;
        run += counts[i];
    }
    if (t == 255) row_start[NN_NODES] = part[255];
}

__global__ void fill_kernel(const int* __restrict__ ei, const int* __restrict__ row_start,
                            int* __restrict__ cursor, int* __restrict__ slot_pos) {
    int e = blockIdx.x * 256 + threadIdx.x;
    if (e < NE_EDGES) {
        int d = ei[NE_EDGES + e];
        int p = atomicAdd(&cursor[d], 1);
        slot_pos[e] = row_start[d] + p;
    }
}

// ---------------------------------------------------------------------------
// Edge prep (CSR slot order). All 8 kidx of an edge pairwise DISTINCT.
// ---------------------------------------------------------------------------
__global__ void edge_prep_sorted(const float* __restrict__ pseudo, const int* __restrict__ ei,
                                 const int* __restrict__ slot_pos,
                                 int* __restrict__ srcs,
                                 float* __restrict__ bas8, unsigned char* __restrict__ kidb) {
    int e = blockIdx.x * 256 + threadIdx.x;
    if (e >= NE_EDGES) return;
    const int ksa[3] = {3, 8, 2};
    float frac[3];
    int id_lo[3], id_hi[3];
#pragma unroll
    for (int d = 0; d < 3; ++d) {
        float u = pseudo[e * 3 + d] * (1.0f / 4.5f);
        u = fminf(fmaxf(u, 0.0f), 1.0f);
        float pos = u * (float)(ksa[d] - 1);
        float fl = floorf(pos);
        int lo = (int)fl;
        frac[d] = pos - fl;
        id_lo[d] = lo;
        id_hi[d] = (lo + 1 <= ksa[d] - 1) ? lo + 1 : lo - 1;
    }
    int j = slot_pos[e];
    srcs[j] = ei[e];
#pragma unroll
    for (int s = 0; s < 8; ++s) {
        float w = 1.0f;
        int k = 0;
        const int strides[3] = {16, 2, 1};
#pragma unroll
        for (int d = 0; d < 3; ++d) {
            int bit = (s >> d) & 1;
            k += (bit ? id_hi[d] : id_lo[d]) * strides[d];
            w *= bit ? frac[d] : (1.0f - frac[d]);
        }
        bas8[(size_t)j * 8 + s] = w;
        kidb[(size_t)j * 8 + s] = (unsigned char)k;
    }
}

// ---------------------------------------------------------------------------
// Layer 1 FUSED (c_in = 1): wave per node; emits bf16 h1.
// ---------------------------------------------------------------------------
__global__ __launch_bounds__(256) void layer1_fused_kernel(
    const int* __restrict__ srcs, const float* __restrict__ bas8,
    const unsigned char* __restrict__ kidb, const int* __restrict__ row_start,
    const float* __restrict__ x, const float* __restrict__ W1,
    const float* __restrict__ root1, const float* __restrict__ b1,
    unsigned short* __restrict__ h1bf) {
    __shared__ float w1s[KTOT * 32];
    __shared__ float scopy[4][8 * 49];
    int tid = threadIdx.x;
    for (int l = tid; l < KTOT * 32; l += 256) w1s[l] = W1[l];
    int w = tid >> 6, lane = tid & 63;
    int n = blockIdx.x * 4 + w;
    bool act = n < NN_NODES;
    float* sc = &scopy[w][0];
    for (int l = lane; l < 8 * 49; l += 64) sc[l] = 0.0f;
    if (act) {
        int beg = row_start[n], end = row_start[n + 1];
        int es = lane >> 3;
        for (int jb = beg; jb < end; jb += 8) {
            int j = jb + es;
            if (j < end) {
                float b = bas8[(size_t)jb * 8 + lane];
                int k = kidb[(size_t)jb * 8 + lane];
                float xv = x[srcs[j]];
                sc[es * 49 + k] += b * xv;
            }
        }
        if (lane < KTOT) {
            float a = 0.0f;
#pragma unroll
            for (int e = 0; e < 8; ++e) a += sc[e * 49 + lane];
            sc[lane] = a;
        }
    }
    __syncthreads();
    if (act && lane < 32) {
        float s = b1[lane] + x[n] * root1[lane];
#pragma unroll 8
        for (int k = 0; k < KTOT; ++k) s = fmaf(sc[k], w1s[k * 32 + lane], s);
        h1bf[n * 32 + lane] = bf16_rne(fmaxf(s, 0.0f));
    }
}

// ---------------------------------------------------------------------------
// Accumulate via MFMA (layers 2 and 3): one wave per node (round-8/9 proven).
// Emits bf16 row [acc(48*CIN) | h_prev(CIN)] -> Kp = 49*CIN.
// ---------------------------------------------------------------------------
#define BTSTRIDE 40
template <int CIN>
__global__ __launch_bounds__(256) void mfma_acc_kernel(
    const int* __restrict__ srcs, const float* __restrict__ bas8,
    const unsigned char* __restrict__ kidb, const int* __restrict__ row_start,
    const unsigned short* __restrict__ hbf, unsigned short* __restrict__ abuf,
    int n0, int mc) {
    constexpr int NT = CIN / 16;
    __shared__ unsigned short BtAll[4][KTOT * BTSTRIDE];
    int w = threadIdx.x >> 6, lane = threadIdx.x & 63;
    int n_local = blockIdx.x * 4 + w;
    if (n_local >= mc) return;
    int n = n0 + n_local;
    unsigned short* Bt = &BtAll[w][0];
    int q = lane >> 4;
    int l15 = lane & 15;
    int beg = row_start[n], end = row_start[n + 1];
    int cnt = end - beg;
    f32x4 acc[3][NT] = {};

    for (int c0 = 0; c0 < cnt; c0 += 32) {
        uint4 z = make_uint4(0, 0, 0, 0);
        for (int l = lane; l < (KTOT * BTSTRIDE) / 8; l += 64) ((uint4*)Bt)[l] = z;
#pragma unroll
        for (int it = 0; it < 4; ++it) {
            int idx = it * 64 + lane;
            int jj = idx >> 3, s = idx & 7;
            int j = c0 + jj;
            if (j < cnt) {
                float b = bas8[(size_t)(beg + j) * 8 + s];
                int k = kidb[(size_t)(beg + j) * 8 + s];
                Bt[k * BTSTRIDE + jj] = bf16_rne(b);
            }
        }
        int srcv[8];
#pragma unroll
        for (int j = 0; j < 8; ++j) {
            int jc = c0 + q * 8 + j;
            jc = (jc < cnt) ? jc : (cnt - 1);
            srcv[j] = srcs[beg + jc];
        }
        bf16x8 afr[3];
#pragma unroll
        for (int mt = 0; mt < 3; ++mt) {
            uint4 raw = *(const uint4*)&Bt[(mt * 16 + l15) * BTSTRIDE + q * 8];
            afr[mt] = __builtin_bit_cast(bf16x8, raw);
        }
#pragma unroll
        for (int nt = 0; nt < NT; ++nt) {
            unsigned int bw[4];
#pragma unroll
            for (int jp = 0; jp < 4; ++jp) {
                unsigned int lo = hbf[(size_t)srcv[2 * jp] * CIN + nt * 16 + l15];
                unsigned int hi = hbf[(size_t)srcv[2 * jp + 1] * CIN + nt * 16 + l15];
                bw[jp] = lo | (hi << 16);
            }
            uint4 braw = make_uint4(bw[0], bw[1], bw[2], bw[3]);
            bf16x8 bfr = __builtin_bit_cast(bf16x8, braw);
#pragma unroll
            for (int mt = 0; mt < 3; ++mt)
                acc[mt][nt] = __builtin_amdgcn_mfma_f32_16x16x32_bf16(afr[mt], bfr,
                                                                      acc[mt][nt], 0, 0, 0);
        }
    }

    unsigned short* arow = abuf + (size_t)n_local * (49 * CIN);
#pragma unroll
    for (int mt = 0; mt < 3; ++mt)
#pragma unroll
        for (int nt = 0; nt < NT; ++nt)
#pragma unroll
            for (int r = 0; r < 4; ++r) {
                int kk = mt * 16 + q * 4 + r;
                int ch = nt * 16 + l15;
                arow[kk * CIN + ch] = bf16_rne(acc[mt][nt][r]);
            }
    if (lane < CIN) arow[KTOT * CIN + lane] = hbf[(size_t)n * CIN + lane];
}

// ---------------------------------------------------------------------------
// Pack W' = [W(KK rows); root(CP rows)] into MFMA B-fragment order.
// ---------------------------------------------------------------------------
__global__ void pack_w_kernel(const float* __restrict__ W, const float* __restrict__ root,
                              int KK, int NN, int total, unsigned short* __restrict__ Wp) {
    int tid = blockIdx.x * 256 + threadIdx.x;
    if (tid >= total) return;
    int nct = NN >> 4;
    int l = tid & 63;
    int c = (tid >> 6) % nct;
    int t = tid / (64 * nct);
    int n = c * 16 + (l & 15);
    int kbase = t * 32 + ((l >> 4) << 3);
    unsigned short vals[8];
#pragma unroll
    for (int jj = 0; jj < 8; ++jj) {
        int k = kbase + jj;
        float v = (k < KK) ? W[(size_t)k * NN + n] : root[(size_t)(k - KK) * NN + n];
        vals[jj] = bf16_rne(v);
    }
    *(uint4*)&Wp[(size_t)tid * 8] = *(uint4*)vals;
}

// ---------------------------------------------------------------------------
// K-split MFMA GEMM, 2 row-tiles/wave, software-pipelined: A/B fragments for
// t+1 are loaded into registers before the MFMA block of t (loads issue at
// the top of each iteration's compute, consumed one iteration later).
//   outsum[n0+r, col] += Arow[r, Krange] @ W'[Krange, col]
// blockIdx.y = K-segment; fp32 atomic accumulate; bias/ReLU in epilogues.
// ---------------------------------------------------------------------------
template <int NCT, int KSPLIT>
__global__ __launch_bounds__(256) void mfma_gemm_atomic(
    const unsigned short* __restrict__ A, const unsigned short* __restrict__ Wp,
    float* __restrict__ outsum, int Kp, int n0, int mc) {
    constexpr int NN = NCT * 16;
    int w = threadIdx.x >> 6, lane = threadIdx.x & 63;
    int rl0 = blockIdx.x * 128 + w * 32 + (lane & 15);   // row-tile 0
    int rl1 = rl0 + 16;                                   // row-tile 1
    int rc0 = min(rl0, mc - 1);
    int rc1 = min(rl1, mc - 1);
    const unsigned short* arow0 = A + (size_t)rc0 * Kp + ((lane >> 4) << 3);
    const unsigned short* arow1 = A + (size_t)rc1 * Kp + ((lane >> 4) << 3);
    const uint4* wpq = (const uint4*)Wp;
    f32x4 acc0[NCT] = {};
    f32x4 acc1[NCT] = {};
    int tsteps = Kp >> 5;
    int t0 = (blockIdx.y * tsteps) / KSPLIT;
    int t1 = ((blockIdx.y + 1) * tsteps) / KSPLIT;

    // prologue prefetch
    uint4 na0 = *(const uint4*)(arow0 + t0 * 32);
    uint4 na1 = *(const uint4*)(arow1 + t0 * 32);
    uint4 nb[NCT];
    {
        const uint4* bb = wpq + ((size_t)t0 * NCT) * 64 + lane;
#pragma unroll
        for (int c = 0; c < NCT; ++c) nb[c] = bb[c * 64];
    }
    for (int t = t0; t < t1; ++t) {
        uint4 ca0 = na0, ca1 = na1;
        uint4 cb[NCT];
#pragma unroll
        for (int c = 0; c < NCT; ++c) cb[c] = nb[c];
        int tn = (t + 1 < t1) ? t + 1 : t;   // clamped (harmless reload on last)
        na0 = *(const uint4*)(arow0 + tn * 32);
        na1 = *(const uint4*)(arow1 + tn * 32);
        const uint4* bb = wpq + ((size_t)tn * NCT) * 64 + lane;
#pragma unroll
        for (int c = 0; c < NCT; ++c) nb[c] = bb[c * 64];
        bf16x8 af0 = __builtin_bit_cast(bf16x8, ca0);
        bf16x8 af1 = __builtin_bit_cast(bf16x8, ca1);
#pragma unroll
        for (int c = 0; c < NCT; ++c) {
            bf16x8 bfr = __builtin_bit_cast(bf16x8, cb[c]);
            acc0[c] = __builtin_amdgcn_mfma_f32_16x16x32_bf16(af0, bfr, acc0[c], 0, 0, 0);
            acc1[c] = __builtin_amdgcn_mfma_f32_16x16x32_bf16(af1, bfr, acc1[c], 0, 0, 0);
        }
    }
    int col0 = lane & 15;
    int rb0 = blockIdx.x * 128 + w * 32 + ((lane >> 4) << 2);
    int rb1 = rb0 + 16;
#pragma unroll
    for (int c = 0; c < NCT; ++c) {
        int col = c * 16 + col0;
#pragma unroll
        for (int r = 0; r < 4; ++r) {
            int ro0 = rb0 + r;
            if (ro0 < mc)
                atomicAdd(&outsum[(size_t)(n0 + ro0) * NN + col], acc0[c][r]);
            int ro1 = rb1 + r;
            if (ro1 < mc)
                atomicAdd(&outsum[(size_t)(n0 + ro1) * NN + col], acc1[c][r]);
        }
    }
}

// ---------------------------------------------------------------------------
// Layer-2 epilogue: h2bf = bf16(relu(h2sum + b2)).
// ---------------------------------------------------------------------------
__global__ void h2_epilogue_kernel(const float* __restrict__ h2sum,
                                   const float* __restrict__ b2,
                                   unsigned short* __restrict__ h2bf) {
    int i = blockIdx.x * 256 + threadIdx.x;
    if (i < NN_NODES * 64)
        h2bf[i] = bf16_rne(fmaxf(h2sum[i] + b2[i & 63], 0.0f));
}

// ---------------------------------------------------------------------------
// Final epilogue: bias + relu + log_softmax over rows of out[N,128], in place.
// ---------------------------------------------------------------------------
__global__ void final_kernel(float* __restrict__ out, const float* __restrict__ b3) {
    int n = blockIdx.x;
    int lane = threadIdx.x;
    float v0 = fmaxf(out[(size_t)n * 128 + lane] + b3[lane], 0.0f);
    float v1 = fmaxf(out[(size_t)n * 128 + 64 + lane] + b3[64 + lane], 0.0f);
    float m = fmaxf(v0, v1);
#pragma unroll
    for (int off = 32; off > 0; off >>= 1) m = fmaxf(m, __shfl_xor(m, off));
    float s = expf(v0 - m) + expf(v1 - m);
#pragma unroll
    for (int off = 32; off > 0; off >>= 1) s += __shfl_xor(s, off);
    float lse = m + logf(s);
    out[(size_t)n * 128 + lane] = v0 - lse;
    out[(size_t)n * 128 + 64 + lane] = v1 - lse;
}

// ---------------------------------------------------------------------------
// Launch
// ---------------------------------------------------------------------------
extern "C" void kernel_launch(void* const* d_in, const int* in_sizes, int n_in,
                              void* d_out, int out_size, void* d_ws, size_t ws_size,
                              hipStream_t stream) {
    const float* x = (const float*)d_in[0];
    const int* ei = (const int*)d_in[1];
    const float* pseudo = (const float*)d_in[2];
    const float* W1 = (const float*)d_in[3];
    const float* root1 = (const float*)d_in[4];
    const float* b1 = (const float*)d_in[5];
    const float* W2 = (const float*)d_in[6];
    const float* root2 = (const float*)d_in[7];
    const float* b2 = (const float*)d_in[8];
    const float* W3 = (const float*)d_in[9];
    const float* root3 = (const float*)d_in[10];
    const float* b3 = (const float*)d_in[11];
    float* out = (float*)d_out;
    char* ws = (char*)d_ws;

    const int N = NN_NODES, E = NE_EDGES;
    const int Kp2 = 49 * 32;   // 1568
    const int Kp3 = 49 * 64;   // 3136
    size_t off = 0;
    auto carve = [&](size_t bytes) {
        size_t p = off;
        off += (bytes + 255) & ~(size_t)255;
        return p;
    };
    int* counts = (int*)(ws + carve((size_t)N * 4 * 2));
    int* cursor = counts + N;
    int* row_start = (int*)(ws + carve((size_t)(N + 1) * 4));
    int* slot_pos = (int*)(ws + carve((size_t)E * 4));
    int* srcs = (int*)(ws + carve((size_t)E * 4));
    float* bas8 = (float*)(ws + carve((size_t)E * 8 * 4));
    unsigned char* kidb = (unsigned char*)(ws + carve((size_t)E * 8));
    unsigned short* h1bf = (unsigned short*)(ws + carve((size_t)N * 32 * 2));
    unsigned short* h2bf = (unsigned short*)(ws + carve((size_t)N * 64 * 2));
    float* h2sum = (float*)(ws + carve((size_t)N * 64 * 4));
    unsigned short* Wp2 = (unsigned short*)(ws + carve((size_t)Kp2 * 64 * 2));
    unsigned short* Wp3 = (unsigned short*)(ws + carve((size_t)Kp3 * 128 * 2));
    size_t rem = (ws_size > off) ? (ws_size - off) : 0;
    unsigned short* abuf = (unsigned short*)(ws + off);

    int ch2 = (int)(rem / ((size_t)Kp2 * 2));
    int ch3 = (int)(rem / ((size_t)Kp3 * 2));
    if (ch2 > N) ch2 = N;
    if (ch3 > N) ch3 = N;
    if (ch2 < 1) ch2 = 1;
    if (ch3 < 1) ch3 = 1;

    int egrid = (E + 255) / 256;

    // CSR + sorted edge metadata
    zero_kernel<<<(2 * N + 255) / 256, 256, 0, stream>>>(counts, 2 * N);
    count_kernel<<<egrid, 256, 0, stream>>>(ei, counts);
    scan_kernel<<<1, 256, 0, stream>>>(counts, row_start);
    fill_kernel<<<egrid, 256, 0, stream>>>(ei, row_start, cursor, slot_pos);
    edge_prep_sorted<<<egrid, 256, 0, stream>>>(pseudo, ei, slot_pos, srcs, bas8, kidb);

    // pack weights + zero the fp32 sum buffers
    int tot2 = (Kp2 / 32) * (64 / 16) * 64;
    int tot3 = (Kp3 / 32) * (128 / 16) * 64;
    pack_w_kernel<<<(tot2 + 255) / 256, 256, 0, stream>>>(W2, root2, KTOT * 32, 64, tot2, Wp2);
    pack_w_kernel<<<(tot3 + 255) / 256, 256, 0, stream>>>(W3, root3, KTOT * 64, 128, tot3, Wp3);
    zero_kernel<<<(N * 64 + 255) / 256, 256, 0, stream>>>((int*)h2sum, N * 64);
    zero_kernel<<<(N * 128 + 255) / 256, 256, 0, stream>>>((int*)out, N * 128);

    // layer 1 (fused accumulate + dense + relu) -> bf16 h1
    layer1_fused_kernel<<<(N + 3) / 4, 256, 0, stream>>>(srcs, bas8, kidb, row_start, x,
                                                         W1, root1, b1, h1bf);

    // layer 2 (MFMA accumulate -> pipelined K-split atomic GEMM)
    for (int n0 = 0; n0 < N; n0 += ch2) {
        int mc = N - n0 < ch2 ? N - n0 : ch2;
        mfma_acc_kernel<32><<<(mc + 3) / 4, 256, 0, stream>>>(
            srcs, bas8, kidb, row_start, h1bf, abuf, n0, mc);
        dim3 g2((mc + 127) / 128, 8);
        mfma_gemm_atomic<4, 8><<<g2, 256, 0, stream>>>(abuf, Wp2, h2sum, Kp2, n0, mc);
    }
    h2_epilogue_kernel<<<(N * 64 + 255) / 256, 256, 0, stream>>>(h2sum, b2, h2bf);

    // layer 3 (MFMA accumulate -> pipelined K-split atomic GEMM)
    for (int n0 = 0; n0 < N; n0 += ch3) {
        int mc = N - n0 < ch3 ? N - n0 : ch3;
        mfma_acc_kernel<64><<<(mc + 3) / 4, 256, 0, stream>>>(
            srcs, bas8, kidb, row_start, h2bf, abuf, n0, mc);
        dim3 g3((mc + 127) / 128, 8);
        mfma_gemm_atomic<8, 8><<<g3, 256, 0, stream>>>(abuf, Wp3, out, Kp3, n0, mc);
    }

    // bias + relu + log_softmax (in place on d_out)
    final_kernel<<<N, 64, 0, stream>>>(out, b3);
}

// Round 13
// 346.964 us; speedup vs baseline: 1.1714x; 1.1714x over previous
//
#include <hip/hip_runtime.h>
#include <hip/hip_bf16.h>

#define NN_NODES 20000
#define NE_EDGES 500000
#define KTOT 48

typedef __bf16 bf16x8 __attribute__((ext_vector_type(8)));
typedef float f32x4 __attribute__((ext_vector_type(4)));

__device__ inline unsigned short bf16_rne(float x) {
    unsigned int u = __float_as_uint(x);
    u = (u + 0x7fffu + ((u >> 16) & 1u)) >> 16;
    return (unsigned short)u;
}

// ---------------------------------------------------------------------------
// Zero helper
// ---------------------------------------------------------------------------
__global__ void zero_kernel(int* __restrict__ p, int n) {
    int i = blockIdx.x * 256 + threadIdx.x;
    if (i < n) p[i] = 0;
}

// ---------------------------------------------------------------------------
// CSR build
// ---------------------------------------------------------------------------
__global__ void count_kernel(const int* __restrict__ ei, int* __restrict__ counts) {
    int e = blockIdx.x * 256 + threadIdx.x;
    if (e < NE_EDGES) atomicAdd(&counts[ei[NE_EDGES + e]], 1);
}

__global__ void scan_kernel(const int* __restrict__ counts, int* __restrict__ row_start) {
    __shared__ int part[256];
    const int CH = (NN_NODES + 255) / 256;
    int t = threadIdx.x;
    int begin = t * CH;
    int end = begin + CH;
    if (end > NN_NODES) end = NN_NODES;
    int sum = 0;
    for (int i = begin; i < end && i < NN_NODES; ++i) sum += counts[i];
    part[t] = sum;
    __syncthreads();
    for (int off = 1; off < 256; off <<= 1) {
        int v = (t >= off) ? part[t - off] : 0;
        __syncthreads();
        part[t] += v;
        __syncthreads();
    }
    int run = (t == 0) ? 0 : part[t - 1];
    for (int i = begin; i < end && i < NN_NODES; ++i) {
        row_start[i] = run;
        run += counts[i];
    }
    if (t == 255) row_start[NN_NODES] = part[255];
}

__global__ void fill_kernel(const int* __restrict__ ei, const int* __restrict__ row_start,
                            int* __restrict__ cursor, int* __restrict__ slot_pos) {
    int e = blockIdx.x * 256 + threadIdx.x;
    if (e < NE_EDGES) {
        int d = ei[NE_EDGES + e];
        int p = atomicAdd(&cursor[d], 1);
        slot_pos[e] = row_start[d] + p;
    }
}

// ---------------------------------------------------------------------------
// Edge prep (CSR slot order). All 8 kidx of an edge pairwise DISTINCT.
// ---------------------------------------------------------------------------
__global__ void edge_prep_sorted(const float* __restrict__ pseudo, const int* __restrict__ ei,
                                 const int* __restrict__ slot_pos,
                                 int* __restrict__ srcs,
                                 float* __restrict__ bas8, unsigned char* __restrict__ kidb) {
    int e = blockIdx.x * 256 + threadIdx.x;
    if (e >= NE_EDGES) return;
    const int ksa[3] = {3, 8, 2};
    float frac[3];
    int id_lo[3], id_hi[3];
#pragma unroll
    for (int d = 0; d < 3; ++d) {
        float u = pseudo[e * 3 + d] * (1.0f / 4.5f);
        u = fminf(fmaxf(u, 0.0f), 1.0f);
        float pos = u * (float)(ksa[d] - 1);
        float fl = floorf(pos);
        int lo = (int)fl;
        frac[d] = pos - fl;
        id_lo[d] = lo;
        id_hi[d] = (lo + 1 <= ksa[d] - 1) ? lo + 1 : lo - 1;
    }
    int j = slot_pos[e];
    srcs[j] = ei[e];
#pragma unroll
    for (int s = 0; s < 8; ++s) {
        float w = 1.0f;
        int k = 0;
        const int strides[3] = {16, 2, 1};
#pragma unroll
        for (int d = 0; d < 3; ++d) {
            int bit = (s >> d) & 1;
            k += (bit ? id_hi[d] : id_lo[d]) * strides[d];
            w *= bit ? frac[d] : (1.0f - frac[d]);
        }
        bas8[(size_t)j * 8 + s] = w;
        kidb[(size_t)j * 8 + s] = (unsigned char)k;
    }
}

// ---------------------------------------------------------------------------
// Layer 1 FUSED (c_in = 1): wave per node; emits bf16 h1.
// ---------------------------------------------------------------------------
__global__ __launch_bounds__(256) void layer1_fused_kernel(
    const int* __restrict__ srcs, const float* __restrict__ bas8,
    const unsigned char* __restrict__ kidb, const int* __restrict__ row_start,
    const float* __restrict__ x, const float* __restrict__ W1,
    const float* __restrict__ root1, const float* __restrict__ b1,
    unsigned short* __restrict__ h1bf) {
    __shared__ float w1s[KTOT * 32];
    __shared__ float scopy[4][8 * 49];
    int tid = threadIdx.x;
    for (int l = tid; l < KTOT * 32; l += 256) w1s[l] = W1[l];
    int w = tid >> 6, lane = tid & 63;
    int n = blockIdx.x * 4 + w;
    bool act = n < NN_NODES;
    float* sc = &scopy[w][0];
    for (int l = lane; l < 8 * 49; l += 64) sc[l] = 0.0f;
    if (act) {
        int beg = row_start[n], end = row_start[n + 1];
        int es = lane >> 3;
        for (int jb = beg; jb < end; jb += 8) {
            int j = jb + es;
            if (j < end) {
                float b = bas8[(size_t)jb * 8 + lane];
                int k = kidb[(size_t)jb * 8 + lane];
                float xv = x[srcs[j]];
                sc[es * 49 + k] += b * xv;
            }
        }
        if (lane < KTOT) {
            float a = 0.0f;
#pragma unroll
            for (int e = 0; e < 8; ++e) a += sc[e * 49 + lane];
            sc[lane] = a;
        }
    }
    __syncthreads();
    if (act && lane < 32) {
        float s = b1[lane] + x[n] * root1[lane];
#pragma unroll 8
        for (int k = 0; k < KTOT; ++k) s = fmaf(sc[k], w1s[k * 32 + lane], s);
        h1bf[n * 32 + lane] = bf16_rne(fmaxf(s, 0.0f));
    }
}

// ---------------------------------------------------------------------------
// Accumulate via MFMA (layers 2 and 3): one wave per node (round-8/9 proven).
// Emits bf16 row [acc(48*CIN) | h_prev(CIN)] -> Kp = 49*CIN.
// ---------------------------------------------------------------------------
#define BTSTRIDE 40
template <int CIN>
__global__ __launch_bounds__(256) void mfma_acc_kernel(
    const int* __restrict__ srcs, const float* __restrict__ bas8,
    const unsigned char* __restrict__ kidb, const int* __restrict__ row_start,
    const unsigned short* __restrict__ hbf, unsigned short* __restrict__ abuf,
    int n0, int mc) {
    constexpr int NT = CIN / 16;
    __shared__ unsigned short BtAll[4][KTOT * BTSTRIDE];
    int w = threadIdx.x >> 6, lane = threadIdx.x & 63;
    int n_local = blockIdx.x * 4 + w;
    if (n_local >= mc) return;
    int n = n0 + n_local;
    unsigned short* Bt = &BtAll[w][0];
    int q = lane >> 4;
    int l15 = lane & 15;
    int beg = row_start[n], end = row_start[n + 1];
    int cnt = end - beg;
    f32x4 acc[3][NT] = {};

    for (int c0 = 0; c0 < cnt; c0 += 32) {
        uint4 z = make_uint4(0, 0, 0, 0);
        for (int l = lane; l < (KTOT * BTSTRIDE) / 8; l += 64) ((uint4*)Bt)[l] = z;
#pragma unroll
        for (int it = 0; it < 4; ++it) {
            int idx = it * 64 + lane;
            int jj = idx >> 3, s = idx & 7;
            int j = c0 + jj;
            if (j < cnt) {
                float b = bas8[(size_t)(beg + j) * 8 + s];
                int k = kidb[(size_t)(beg + j) * 8 + s];
                Bt[k * BTSTRIDE + jj] = bf16_rne(b);
            }
        }
        int srcv[8];
#pragma unroll
        for (int j = 0; j < 8; ++j) {
            int jc = c0 + q * 8 + j;
            jc = (jc < cnt) ? jc : (cnt - 1);
            srcv[j] = srcs[beg + jc];
        }
        bf16x8 afr[3];
#pragma unroll
        for (int mt = 0; mt < 3; ++mt) {
            uint4 raw = *(const uint4*)&Bt[(mt * 16 + l15) * BTSTRIDE + q * 8];
            afr[mt] = __builtin_bit_cast(bf16x8, raw);
        }
#pragma unroll
        for (int nt = 0; nt < NT; ++nt) {
            unsigned int bw[4];
#pragma unroll
            for (int jp = 0; jp < 4; ++jp) {
                unsigned int lo = hbf[(size_t)srcv[2 * jp] * CIN + nt * 16 + l15];
                unsigned int hi = hbf[(size_t)srcv[2 * jp + 1] * CIN + nt * 16 + l15];
                bw[jp] = lo | (hi << 16);
            }
            uint4 braw = make_uint4(bw[0], bw[1], bw[2], bw[3]);
            bf16x8 bfr = __builtin_bit_cast(bf16x8, braw);
#pragma unroll
            for (int mt = 0; mt < 3; ++mt)
                acc[mt][nt] = __builtin_amdgcn_mfma_f32_16x16x32_bf16(afr[mt], bfr,
                                                                      acc[mt][nt], 0, 0, 0);
        }
    }

    unsigned short* arow = abuf + (size_t)n_local * (49 * CIN);
#pragma unroll
    for (int mt = 0; mt < 3; ++mt)
#pragma unroll
        for (int nt = 0; nt < NT; ++nt)
#pragma unroll
            for (int r = 0; r < 4; ++r) {
                int kk = mt * 16 + q * 4 + r;
                int ch = nt * 16 + l15;
                arow[kk * CIN + ch] = bf16_rne(acc[mt][nt][r]);
            }
    if (lane < CIN) arow[KTOT * CIN + lane] = hbf[(size_t)n * CIN + lane];
}

// ---------------------------------------------------------------------------
// Pack W' = [W(KK rows); root(CP rows)] into MFMA B-fragment order.
// ---------------------------------------------------------------------------
__global__ void pack_w_kernel(const float* __restrict__ W, const float* __restrict__ root,
                              int KK, int NN, int total, unsigned short* __restrict__ Wp) {
    int tid = blockIdx.x * 256 + threadIdx.x;
    if (tid >= total) return;
    int nct = NN >> 4;
    int l = tid & 63;
    int c = (tid >> 6) % nct;
    int t = tid / (64 * nct);
    int n = c * 16 + (l & 15);
    int kbase = t * 32 + ((l >> 4) << 3);
    unsigned short vals[8];
#pragma unroll
    for (int jj = 0; jj < 8; ++jj) {
        int k = kbase + jj;
        float v = (k < KK) ? W[(size_t)k * NN + n] : root[(size_t)(k - KK) * NN + n];
        vals[jj] = bf16_rne(v);
    }
    *(uint4*)&Wp[(size_t)tid * 8] = *(uint4*)vals;
}

// ---------------------------------------------------------------------------
// Block-internal K-split MFMA GEMM, ZERO atomics.
// Block = 4 waves, M = 16 rows. Each wave computes the full 16xNN tile over
// its K-quarter (register-pipelined), stages fp32 partials in LDS, one
// barrier, then 256 threads reduce and run the fused epilogue:
//   LOGSOFTMAX=false: h2 = bf16(relu(sum + bias))
//   LOGSOFTMAX=true : out = log_softmax(relu(sum + bias)) (fp32, 128 cols)
// ---------------------------------------------------------------------------
template <int NCT, bool LOGSOFTMAX>
__global__ __launch_bounds__(256) void mfma_gemm_block(
    const unsigned short* __restrict__ A, const unsigned short* __restrict__ Wp,
    const float* __restrict__ bias, void* __restrict__ outp,
    int Kp, int n0, int mc) {
    constexpr int NN = NCT * 16;
    constexpr int RSTR = NN + 2;   // padded row stride (floats) -> 2-way max conflicts
    __shared__ float red[4][16 * RSTR];
    int w = threadIdx.x >> 6, lane = threadIdx.x & 63;
    int q = lane >> 4, l15 = lane & 15;
    int row_local = blockIdx.x * 16 + l15;
    int row_c = min(row_local, mc - 1);
    const unsigned short* arow = A + (size_t)row_c * Kp + (q << 3);
    const uint4* wpq = (const uint4*)Wp;
    f32x4 acc[NCT] = {};
    int tsteps = Kp >> 5;
    int t0 = (w * tsteps) >> 2;
    int t1 = ((w + 1) * tsteps) >> 2;

    // prologue prefetch
    uint4 na = *(const uint4*)(arow + t0 * 32);
    uint4 nb[NCT];
    {
        const uint4* bb = wpq + ((size_t)t0 * NCT) * 64 + lane;
#pragma unroll
        for (int c = 0; c < NCT; ++c) nb[c] = bb[c * 64];
    }
    for (int t = t0; t < t1; ++t) {
        uint4 ca = na;
        uint4 cb[NCT];
#pragma unroll
        for (int c = 0; c < NCT; ++c) cb[c] = nb[c];
        int tn = (t + 1 < t1) ? t + 1 : t;   // clamped (harmless reload on last)
        na = *(const uint4*)(arow + tn * 32);
        const uint4* bb = wpq + ((size_t)tn * NCT) * 64 + lane;
#pragma unroll
        for (int c = 0; c < NCT; ++c) nb[c] = bb[c * 64];
        bf16x8 af = __builtin_bit_cast(bf16x8, ca);
#pragma unroll
        for (int c = 0; c < NCT; ++c) {
            bf16x8 bfr = __builtin_bit_cast(bf16x8, cb[c]);
            acc[c] = __builtin_amdgcn_mfma_f32_16x16x32_bf16(af, bfr, acc[c], 0, 0, 0);
        }
    }

    // stage partials: C-layout row = q*4+r, col = c*16+l15
    float* myred = &red[w][0];
#pragma unroll
    for (int c = 0; c < NCT; ++c)
#pragma unroll
        for (int r = 0; r < 4; ++r)
            myred[(q * 4 + r) * RSTR + c * 16 + l15] = acc[c][r];
    __syncthreads();

    if (!LOGSOFTMAX) {
        // layer 2 epilogue: 16 x 64 elems, 4 per thread, coalesced
        unsigned short* outb = (unsigned short*)outp;
        for (int l = threadIdx.x; l < 16 * NN; l += 256) {
            int row = l / NN, col = l % NN;
            int idx = row * RSTR + col;
            float v = red[0][idx] + red[1][idx] + red[2][idx] + red[3][idx];
            v = fmaxf(v + bias[col], 0.0f);
            int ro = blockIdx.x * 16 + row;
            if (ro < mc) outb[(size_t)(n0 + ro) * NN + col] = bf16_rne(v);
        }
    } else {
        // layer 3 epilogue: 16 threads per row, 8 cols each, fused log_softmax
        float* outf = (float*)outp;
        int row = threadIdx.x >> 4;
        int cb0 = threadIdx.x & 15;
        float v[8];
        float mx = -1e30f;
#pragma unroll
        for (int c = 0; c < 8; ++c) {
            int col = cb0 + c * 16;
            int idx = row * RSTR + col;
            float s = red[0][idx] + red[1][idx] + red[2][idx] + red[3][idx];
            s = fmaxf(s + bias[col], 0.0f);
            v[c] = s;
            mx = fmaxf(mx, s);
        }
#pragma unroll
        for (int off = 8; off > 0; off >>= 1) mx = fmaxf(mx, __shfl_xor(mx, off));
        float se = 0.0f;
#pragma unroll
        for (int c = 0; c < 8; ++c) se += expf(v[c] - mx);
#pragma unroll
        for (int off = 8; off > 0; off >>= 1) se += __shfl_xor(se, off);
        float lse = mx + logf(se);
        int ro = blockIdx.x * 16 + row;
        if (ro < mc) {
#pragma unroll
            for (int c = 0; c < 8; ++c)
                outf[(size_t)(n0 + ro) * 128 + cb0 + c * 16] = v[c] - lse;
        }
    }
}

// ---------------------------------------------------------------------------
// Launch
// ---------------------------------------------------------------------------
extern "C" void kernel_launch(void* const* d_in, const int* in_sizes, int n_in,
                              void* d_out, int out_size, void* d_ws, size_t ws_size,
                              hipStream_t stream) {
    const float* x = (const float*)d_in[0];
    const int* ei = (const int*)d_in[1];
    const float* pseudo = (const float*)d_in[2];
    const float* W1 = (const float*)d_in[3];
    const float* root1 = (const float*)d_in[4];
    const float* b1 = (const float*)d_in[5];
    const float* W2 = (const float*)d_in[6];
    const float* root2 = (const float*)d_in[7];
    const float* b2 = (const float*)d_in[8];
    const float* W3 = (const float*)d_in[9];
    const float* root3 = (const float*)d_in[10];
    const float* b3 = (const float*)d_in[11];
    float* out = (float*)d_out;
    char* ws = (char*)d_ws;

    const int N = NN_NODES, E = NE_EDGES;
    const int Kp2 = 49 * 32;   // 1568
    const int Kp3 = 49 * 64;   // 3136
    size_t off = 0;
    auto carve = [&](size_t bytes) {
        size_t p = off;
        off += (bytes + 255) & ~(size_t)255;
        return p;
    };
    int* counts = (int*)(ws + carve((size_t)N * 4 * 2));
    int* cursor = counts + N;
    int* row_start = (int*)(ws + carve((size_t)(N + 1) * 4));
    int* slot_pos = (int*)(ws + carve((size_t)E * 4));
    int* srcs = (int*)(ws + carve((size_t)E * 4));
    float* bas8 = (float*)(ws + carve((size_t)E * 8 * 4));
    unsigned char* kidb = (unsigned char*)(ws + carve((size_t)E * 8));
    unsigned short* h1bf = (unsigned short*)(ws + carve((size_t)N * 32 * 2));
    unsigned short* h2bf = (unsigned short*)(ws + carve((size_t)N * 64 * 2));
    unsigned short* Wp2 = (unsigned short*)(ws + carve((size_t)Kp2 * 64 * 2));
    unsigned short* Wp3 = (unsigned short*)(ws + carve((size_t)Kp3 * 128 * 2));
    size_t rem = (ws_size > off) ? (ws_size - off) : 0;
    unsigned short* abuf = (unsigned short*)(ws + off);

    int ch2 = (int)(rem / ((size_t)Kp2 * 2));
    int ch3 = (int)(rem / ((size_t)Kp3 * 2));
    if (ch2 > N) ch2 = N;
    if (ch3 > N) ch3 = N;
    if (ch2 < 1) ch2 = 1;
    if (ch3 < 1) ch3 = 1;

    int egrid = (E + 255) / 256;

    // CSR + sorted edge metadata
    zero_kernel<<<(2 * N + 255) / 256, 256, 0, stream>>>(counts, 2 * N);
    count_kernel<<<egrid, 256, 0, stream>>>(ei, counts);
    scan_kernel<<<1, 256, 0, stream>>>(counts, row_start);
    fill_kernel<<<egrid, 256, 0, stream>>>(ei, row_start, cursor, slot_pos);
    edge_prep_sorted<<<egrid, 256, 0, stream>>>(pseudo, ei, slot_pos, srcs, bas8, kidb);

    // pack weights (bf16 MFMA B-fragment order)
    int tot2 = (Kp2 / 32) * (64 / 16) * 64;
    int tot3 = (Kp3 / 32) * (128 / 16) * 64;
    pack_w_kernel<<<(tot2 + 255) / 256, 256, 0, stream>>>(W2, root2, KTOT * 32, 64, tot2, Wp2);
    pack_w_kernel<<<(tot3 + 255) / 256, 256, 0, stream>>>(W3, root3, KTOT * 64, 128, tot3, Wp3);

    // layer 1 (fused accumulate + dense + relu) -> bf16 h1
    layer1_fused_kernel<<<(N + 3) / 4, 256, 0, stream>>>(srcs, bas8, kidb, row_start, x,
                                                         W1, root1, b1, h1bf);

    // layer 2 (MFMA accumulate -> block-K-split GEMM, fused bias+relu+bf16)
    for (int n0 = 0; n0 < N; n0 += ch2) {
        int mc = N - n0 < ch2 ? N - n0 : ch2;
        mfma_acc_kernel<32><<<(mc + 3) / 4, 256, 0, stream>>>(
            srcs, bas8, kidb, row_start, h1bf, abuf, n0, mc);
        mfma_gemm_block<4, false><<<(mc + 15) / 16, 256, 0, stream>>>(
            abuf, Wp2, b2, h2bf, Kp2, n0, mc);
    }

    // layer 3 (MFMA accumulate -> block-K-split GEMM, fused bias+relu+logsoftmax)
    for (int n0 = 0; n0 < N; n0 += ch3) {
        int mc = N - n0 < ch3 ? N - n0 : ch3;
        mfma_acc_kernel<64><<<(mc + 3) / 4, 256, 0, stream>>>(
            srcs, bas8, kidb, row_start, h2bf, abuf, n0, mc);
        mfma_gemm_block<8, true><<<(mc + 15) / 16, 256, 0, stream>>>(
            abuf, Wp3, b3, out, Kp3, n0, mc);
    }
}